// Round 1
// baseline (1159.162 us; speedup 1.0000x reference)
//
#include <hip/hip_runtime.h>

#define N_NODES 50000
#define N_EDGES 800000
#define NBATCH 32
#define HWDIM 128
#define IMG (HWDIM * HWDIM)
#define HID 128

// ---------------------------------------------------------------------------
// Conv 3x3 SAME, NCHW. One thread per (n,y,x) pixel, all COUT channels in regs.
// Weights indexed by compile-time-constant offsets -> scalar loads.
// ---------------------------------------------------------------------------
template <int CIN, int COUT, bool RELU>
__global__ __launch_bounds__(256) void conv3x3_kernel(
    const float* __restrict__ in, const float* __restrict__ w,
    const float* __restrict__ bias, float* __restrict__ out) {
  int t = blockIdx.x * blockDim.x + threadIdx.x;  // 0 .. 32*128*128-1
  int x = t & (HWDIM - 1);
  int y = (t >> 7) & (HWDIM - 1);
  int n = t >> 14;
  const float* inb = in + (size_t)n * CIN * IMG;
  float acc[COUT];
#pragma unroll
  for (int co = 0; co < COUT; ++co) acc[co] = bias[co];
#pragma unroll
  for (int dy = 0; dy < 3; ++dy) {
    int yy = y + dy - 1;
    bool vy = (unsigned)yy < HWDIM;
    int yc = vy ? yy : 0;
#pragma unroll
    for (int dx = 0; dx < 3; ++dx) {
      int xx = x + dx - 1;
      bool vv = vy && ((unsigned)xx < HWDIM);
      int xc = vv ? xx : 0;
#pragma unroll
      for (int ci = 0; ci < CIN; ++ci) {
        float val = inb[ci * IMG + yc * HWDIM + xc];
        val = vv ? val : 0.0f;
#pragma unroll
        for (int co = 0; co < COUT; ++co)
          acc[co] += val * w[(co * CIN + ci) * 9 + dy * 3 + dx];
      }
    }
  }
  float* ob = out + (size_t)n * COUT * IMG + y * HWDIM + x;
#pragma unroll
  for (int co = 0; co < COUT; ++co) {
    float v = acc[co];
    if (RELU) v = fmaxf(v, 0.0f);
    ob[(size_t)co * IMG] = v;
  }
}

// ---------------------------------------------------------------------------
// small utility kernels
// ---------------------------------------------------------------------------
__global__ void zero_int_kernel(int* __restrict__ p, int n) {
  int t = blockIdx.x * blockDim.x + threadIdx.x;
  if (t < n) p[t] = 0;
}

__global__ void hist_kernel(const int* __restrict__ ei, int* __restrict__ hist) {
  int e = blockIdx.x * blockDim.x + threadIdx.x;
  if (e < N_EDGES) atomicAdd(&hist[ei[N_EDGES + e]], 1);
}

// single-block scan over N=50000: row_ptr[0]=0; row_ptr[i+1]=incl_prefix(hist)[i]
__global__ __launch_bounds__(1024) void scan_kernel(const int* __restrict__ hist,
                                                    int* __restrict__ row_ptr, int n) {
  __shared__ int buf[1024];
  __shared__ int carry_s;
  if (threadIdx.x == 0) {
    row_ptr[0] = 0;
    carry_s = 0;
  }
  __syncthreads();
  for (int base = 0; base < n; base += 1024) {
    int idx = base + threadIdx.x;
    int v = (idx < n) ? hist[idx] : 0;
    buf[threadIdx.x] = v;
    __syncthreads();
    for (int off = 1; off < 1024; off <<= 1) {
      int tv = (threadIdx.x >= off) ? buf[threadIdx.x - off] : 0;
      __syncthreads();
      buf[threadIdx.x] += tv;
      __syncthreads();
    }
    int carry = carry_s;
    if (idx < n) row_ptr[idx + 1] = carry + buf[threadIdx.x];
    int total = buf[1023];
    __syncthreads();
    if (threadIdx.x == 0) carry_s = carry + total;
    __syncthreads();
  }
}

__global__ void copy_int_kernel(const int* __restrict__ src, int* __restrict__ dst, int n) {
  int t = blockIdx.x * blockDim.x + threadIdx.x;
  if (t < n) dst[t] = src[t];
}

__global__ void scatter_kernel(const int* __restrict__ ei, int* __restrict__ cursor,
                               int* __restrict__ csr) {
  int e = blockIdx.x * blockDim.x + threadIdx.x;
  if (e < N_EDGES) {
    int d = ei[N_EDGES + e];
    int p = atomicAdd(&cursor[d], 1);
    csr[p] = ei[e];
  }
}

// ---------------------------------------------------------------------------
// gather node features: gx = [x0, x1, x5, x6, x7, pos0, pos1, cnng]
// ---------------------------------------------------------------------------
__global__ void gather_gx_kernel(const float* __restrict__ x, const float* __restrict__ pos,
                                 const int* __restrict__ batch, const float* __restrict__ x1,
                                 float* __restrict__ gx) {
  int t = blockIdx.x * blockDim.x + threadIdx.x;
  if (t >= N_NODES) return;
  float px = pos[2 * t + 0];
  float py = pos[2 * t + 1];
  float fx = px / 20.0f * 127.0f;
  float fy = py / 20.0f * 127.0f;
  int cx = (int)rintf(fx);
  int cy = (int)rintf(fy);
  cx = min(max(cx, 0), HWDIM - 1);
  cy = min(max(cy, 0), HWDIM - 1);
  int b = batch[t];
  float cn = x1[(size_t)b * IMG + cy * HWDIM + cx];
  const float* xr = x + (size_t)t * 8;
  float* g = gx + (size_t)t * 8;
  g[0] = xr[0];
  g[1] = xr[1];
  g[2] = xr[5];
  g[3] = xr[6];
  g[4] = xr[7];
  g[5] = px;
  g[6] = py;
  g[7] = cn;
}

// ---------------------------------------------------------------------------
// CSR aggregation, C=8: 8 lanes per node
// ---------------------------------------------------------------------------
__global__ void agg8_kernel(const float* __restrict__ gx, const int* __restrict__ row_ptr,
                            const int* __restrict__ csr, float* __restrict__ out) {
  int t = blockIdx.x * blockDim.x + threadIdx.x;
  int i = t >> 3;
  int f = t & 7;
  if (i >= N_NODES) return;
  int beg = row_ptr[i], end = row_ptr[i + 1];
  float acc = 0.0f;
  for (int k = beg; k < end; ++k) acc += gx[(size_t)csr[k] * 8 + f];
  out[(size_t)i * 8 + f] = acc / fmaxf((float)(end - beg), 1.0f);
}

// CSR aggregation, C=128: one wave per node, float2 per lane
__global__ __launch_bounds__(256) void agg128_kernel(const float* __restrict__ h,
                                                     const int* __restrict__ row_ptr,
                                                     const int* __restrict__ csr,
                                                     float* __restrict__ out) {
  int wid = (blockIdx.x * blockDim.x + threadIdx.x) >> 6;
  int lane = threadIdx.x & 63;
  if (wid >= N_NODES) return;
  int beg = row_ptr[wid], end = row_ptr[wid + 1];
  float ax = 0.0f, ay = 0.0f;
  const float* hp = h + 2 * lane;
  for (int k = beg; k < end; ++k) {
    int s = csr[k];
    float2 v = *(const float2*)(hp + (size_t)s * HID);
    ax += v.x;
    ay += v.y;
  }
  float inv = 1.0f / fmaxf((float)(end - beg), 1.0f);
  float2 o;
  o.x = ax * inv;
  o.y = ay * inv;
  *(float2*)(out + (size_t)wid * HID + 2 * lane) = o;
}

// ---------------------------------------------------------------------------
// layer1: out[i][j] = relu( sum_k agg8[i][k]*Wl[j][k] + gx[i][k]*Wr[j][k] + b[j] )
// ---------------------------------------------------------------------------
__global__ __launch_bounds__(256) void layer1_kernel(const float* __restrict__ agg8,
                                                     const float* __restrict__ gx,
                                                     const float* __restrict__ Wl,
                                                     const float* __restrict__ Wr,
                                                     const float* __restrict__ b,
                                                     float* __restrict__ out) {
  __shared__ float wl[8][128];
  __shared__ float wr[8][128];
  for (int t = threadIdx.x; t < 1024; t += 256) {
    int j = t >> 3, k = t & 7;
    wl[k][j] = Wl[t];
    wr[k][j] = Wr[t];
  }
  __syncthreads();
  int t = blockIdx.x * blockDim.x + threadIdx.x;
  int i = t >> 7;
  int j = t & 127;
  if (i >= N_NODES) return;
  const float* a = agg8 + (size_t)i * 8;
  const float* g = gx + (size_t)i * 8;
  float acc = b[j];
#pragma unroll
  for (int k = 0; k < 8; ++k) acc += a[k] * wl[k][j] + g[k] * wr[k][j];
  out[(size_t)i * HID + j] = fmaxf(acc, 0.0f);
}

// ---------------------------------------------------------------------------
// fused SAGE GEMM: C[i][j] = act( sum_k A1[i][k]*W1[j][k] + A2[i][k]*W2[j][k] + b[j] )
// 64x64 tile, BK=16, 256 threads, 4x4 microtile.
// ---------------------------------------------------------------------------
__global__ __launch_bounds__(256) void sage_gemm_kernel(
    const float* __restrict__ A1, const float* __restrict__ A2,
    const float* __restrict__ W1, const float* __restrict__ W2,
    const float* __restrict__ bias, float* __restrict__ C, int M, int do_relu) {
  __shared__ float As[16][68];
  __shared__ float Bs[16][68];
  int tid = threadIdx.x;
  int tx = tid & 15;
  int ty = tid >> 4;
  int row0 = blockIdx.x * 64;
  int col0 = blockIdx.y * 64;
  float acc[4][4] = {};
  for (int ks = 0; ks < 16; ++ks) {
    const float* A = (ks < 8) ? A1 : A2;
    const float* W = (ks < 8) ? W1 : W2;
    int k0 = (ks & 7) * 16;
    {
      int r = tid >> 2, seg = tid & 3;
      int gr = row0 + r;
      float4 v = make_float4(0.f, 0.f, 0.f, 0.f);
      if (gr < M) v = *(const float4*)(A + (size_t)gr * HID + k0 + seg * 4);
      As[seg * 4 + 0][r] = v.x;
      As[seg * 4 + 1][r] = v.y;
      As[seg * 4 + 2][r] = v.z;
      As[seg * 4 + 3][r] = v.w;
    }
    {
      int j = tid >> 2, seg = tid & 3;
      int gj = col0 + j;
      float4 v = *(const float4*)(W + (size_t)gj * HID + k0 + seg * 4);
      Bs[seg * 4 + 0][j] = v.x;
      Bs[seg * 4 + 1][j] = v.y;
      Bs[seg * 4 + 2][j] = v.z;
      Bs[seg * 4 + 3][j] = v.w;
    }
    __syncthreads();
#pragma unroll
    for (int kk = 0; kk < 16; ++kk) {
      float a[4], b[4];
#pragma unroll
      for (int m = 0; m < 4; ++m) a[m] = As[kk][ty * 4 + m];
#pragma unroll
      for (int n = 0; n < 4; ++n) b[n] = Bs[kk][tx * 4 + n];
#pragma unroll
      for (int m = 0; m < 4; ++m)
#pragma unroll
        for (int n = 0; n < 4; ++n) acc[m][n] += a[m] * b[n];
    }
    __syncthreads();
  }
#pragma unroll
  for (int m = 0; m < 4; ++m) {
    int gi = row0 + ty * 4 + m;
    if (gi >= M) continue;
#pragma unroll
    for (int n = 0; n < 4; ++n) {
      int gj = col0 + tx * 4 + n;
      float v = acc[m][n] + bias[gj];
      if (do_relu) v = fmaxf(v, 0.0f);
      C[(size_t)gi * HID + gj] = v;
    }
  }
}

// ---------------------------------------------------------------------------
// layer4 projections: z[i] = dot(h[i], Wl4), zr[i] = dot(h[i], Wr4). wave/node.
// ---------------------------------------------------------------------------
__global__ __launch_bounds__(256) void zzr_kernel(const float* __restrict__ h,
                                                  const float* __restrict__ Wl4,
                                                  const float* __restrict__ Wr4,
                                                  float* __restrict__ z,
                                                  float* __restrict__ zr) {
  int wid = (blockIdx.x * blockDim.x + threadIdx.x) >> 6;
  int lane = threadIdx.x & 63;
  if (wid >= N_NODES) return;
  float2 v = *(const float2*)(h + (size_t)wid * HID + 2 * lane);
  float2 wl = *(const float2*)(Wl4 + 2 * lane);
  float2 wr = *(const float2*)(Wr4 + 2 * lane);
  float a = v.x * wl.x + v.y * wl.y;
  float b = v.x * wr.x + v.y * wr.y;
#pragma unroll
  for (int off = 32; off > 0; off >>= 1) {
    a += __shfl_xor(a, off, 64);
    b += __shfl_xor(b, off, 64);
  }
  if (lane == 0) {
    z[wid] = a;
    zr[wid] = b;
  }
}

__global__ void gout_kernel(const float* __restrict__ z, const float* __restrict__ zr,
                            const int* __restrict__ row_ptr, const int* __restrict__ csr,
                            const float* __restrict__ bs4, float* __restrict__ gout) {
  int i = blockIdx.x * blockDim.x + threadIdx.x;
  if (i >= N_NODES) return;
  int beg = row_ptr[i], end = row_ptr[i + 1];
  float s = 0.0f;
  for (int k = beg; k < end; ++k) s += z[csr[k]];
  float d = fmaxf((float)(end - beg), 1.0f);
  gout[i] = s / d + zr[i] + bs4[0];
}

// ---------------------------------------------------------------------------
extern "C" void kernel_launch(void* const* d_in, const int* in_sizes, int n_in,
                              void* d_out, int out_size, void* d_ws, size_t ws_size,
                              hipStream_t stream) {
  const float* xdata = (const float*)d_in[0];
  const float* x = (const float*)d_in[1];
  const float* pos = (const float*)d_in[2];
  const int* ei = (const int*)d_in[3];
  const int* batch = (const int*)d_in[4];
  const float* w1 = (const float*)d_in[5];
  const float* b1 = (const float*)d_in[6];
  const float* w2 = (const float*)d_in[7];
  const float* b2 = (const float*)d_in[8];
  const float* w3 = (const float*)d_in[9];
  const float* b3 = (const float*)d_in[10];
  const float* Wl1 = (const float*)d_in[11];
  const float* Wr1 = (const float*)d_in[12];
  const float* bs1 = (const float*)d_in[13];
  const float* Wl2 = (const float*)d_in[14];
  const float* Wr2 = (const float*)d_in[15];
  const float* bs2 = (const float*)d_in[16];
  const float* Wl3 = (const float*)d_in[17];
  const float* Wr3 = (const float*)d_in[18];
  const float* bs3 = (const float*)d_in[19];
  const float* Wl4 = (const float*)d_in[20];
  const float* Wr4 = (const float*)d_in[21];
  const float* bs4 = (const float*)d_in[22];

  float* x1_out = (float*)d_out;                    // 32*1*128*128 = 524288
  float* gout = (float*)d_out + (size_t)NBATCH * IMG;  // N

  char* ws = (char*)d_ws;
  size_t off = 0;
  auto take = [&](size_t bytes) -> char* {
    char* p = ws + off;
    off = (off + bytes + 255) & ~(size_t)255;
    return p;
  };
  float* hbuf1 = (float*)take((size_t)NBATCH * 16 * IMG * 4);  // conv h1 / sage h_a
  float* hbuf2 = (float*)take((size_t)NBATCH * 16 * IMG * 4);  // conv h2 / sage h_b
  float* agg = (float*)take((size_t)N_NODES * HID * 4);
  float* gx = (float*)take((size_t)N_NODES * 8 * 4);
  int* hist = (int*)take((size_t)N_NODES * 4);
  int* row_ptr = (int*)take((size_t)(N_NODES + 1) * 4);
  int* cursor = (int*)take((size_t)N_NODES * 4);
  int* csr = (int*)take((size_t)N_EDGES * 4);
  float* z = (float*)take((size_t)N_NODES * 4);
  float* zr = (float*)take((size_t)N_NODES * 4);
  (void)ws_size;
  (void)xdata;

  const int nblk_n = (N_NODES + 255) / 256;    // 196
  const int nblk_e = (N_EDGES + 255) / 256;    // 3125
  const int nblk_px = (NBATCH * IMG) / 256;    // 2048

  // ---- CNN stack ----
  hipLaunchKernelGGL((conv3x3_kernel<8, 16, true>), dim3(nblk_px), dim3(256), 0, stream,
                     xdata, w1, b1, hbuf1);
  hipLaunchKernelGGL((conv3x3_kernel<16, 16, true>), dim3(nblk_px), dim3(256), 0, stream,
                     hbuf1, w2, b2, hbuf2);
  hipLaunchKernelGGL((conv3x3_kernel<16, 1, false>), dim3(nblk_px), dim3(256), 0, stream,
                     hbuf2, w3, b3, x1_out);

  // ---- CSR build ----
  hipLaunchKernelGGL(zero_int_kernel, dim3(nblk_n), dim3(256), 0, stream, hist, N_NODES);
  hipLaunchKernelGGL(hist_kernel, dim3(nblk_e), dim3(256), 0, stream, ei, hist);
  hipLaunchKernelGGL(scan_kernel, dim3(1), dim3(1024), 0, stream, hist, row_ptr, N_NODES);
  hipLaunchKernelGGL(copy_int_kernel, dim3(nblk_n), dim3(256), 0, stream, row_ptr, cursor,
                     N_NODES);
  hipLaunchKernelGGL(scatter_kernel, dim3(nblk_e), dim3(256), 0, stream, ei, cursor, csr);

  // ---- node features ----
  hipLaunchKernelGGL(gather_gx_kernel, dim3(nblk_n), dim3(256), 0, stream, x, pos, batch,
                     x1_out, gx);

  // ---- layer 1 (K=8) ----
  hipLaunchKernelGGL(agg8_kernel, dim3((N_NODES * 8 + 255) / 256), dim3(256), 0, stream, gx,
                     row_ptr, csr, agg);
  hipLaunchKernelGGL(layer1_kernel, dim3((N_NODES * 128) / 256), dim3(256), 0, stream, agg, gx,
                     Wl1, Wr1, bs1, hbuf1);

  // ---- layer 2 ----
  hipLaunchKernelGGL(agg128_kernel, dim3(N_NODES / 4), dim3(256), 0, stream, hbuf1, row_ptr,
                     csr, agg);
  hipLaunchKernelGGL(sage_gemm_kernel, dim3((N_NODES + 63) / 64, 2), dim3(256), 0, stream, agg,
                     hbuf1, Wl2, Wr2, bs2, hbuf2, N_NODES, 1);

  // ---- layer 3 ----
  hipLaunchKernelGGL(agg128_kernel, dim3(N_NODES / 4), dim3(256), 0, stream, hbuf2, row_ptr,
                     csr, agg);
  hipLaunchKernelGGL(sage_gemm_kernel, dim3((N_NODES + 63) / 64, 2), dim3(256), 0, stream, agg,
                     hbuf2, Wl3, Wr3, bs3, hbuf1, N_NODES, 1);

  // ---- layer 4 (project to scalar first, then aggregate scalars) ----
  hipLaunchKernelGGL(zzr_kernel, dim3(N_NODES / 4), dim3(256), 0, stream, hbuf1, Wl4, Wr4, z,
                     zr);
  hipLaunchKernelGGL(gout_kernel, dim3(nblk_n), dim3(256), 0, stream, z, zr, row_ptr, csr, bs4,
                     gout);
}

// Round 2
// 593.168 us; speedup vs baseline: 1.9542x; 1.9542x over previous
//
#include <hip/hip_runtime.h>

#define N_NODES 50000
#define N_EDGES 800000
#define NBATCH 32
#define HWDIM 128
#define IMG (HWDIM * HWDIM)
#define HID 128

// ---------------------------------------------------------------------------
// Register-blocked conv 3x3 SAME, NCHW.
// Block = 256 threads = 8 rows x 32 threads; each thread computes 4 x-pixels
// for ALL COUT channels (acc[COUT][4]). Inputs: one aligned float4 per
// (ci,row), halos via __shfl. Weights: staged to LDS transposed [ci][tap][co]
// so inner loop uses broadcast ds_read_b128 (COUT%4==0) reused over 4 pixels.
// Grid: 32 images * 16 strips = 512 blocks.
// ---------------------------------------------------------------------------
template <int CIN, int COUT, bool RELU>
__global__ __launch_bounds__(256) void conv3x3_rb_kernel(
    const float* __restrict__ in, const float* __restrict__ w,
    const float* __restrict__ bias, float* __restrict__ out) {
  __shared__ float wlds[CIN * 9 * COUT];
  for (int idx = threadIdx.x; idx < CIN * COUT * 9; idx += 256) {
    int co = idx / (CIN * 9);
    int r = idx - co * CIN * 9;
    int ci = r / 9;
    int tap = r - ci * 9;
    wlds[(ci * 9 + tap) * COUT + co] = w[idx];
  }
  __syncthreads();

  int n = blockIdx.x >> 4;
  int strip = blockIdx.x & 15;
  int y0 = strip * 8 + (threadIdx.x >> 5);
  int x0 = (threadIdx.x & 31) * 4;
  const float* inb = in + (size_t)n * CIN * IMG;

  float acc[COUT][4];
#pragma unroll
  for (int co = 0; co < COUT; ++co)
#pragma unroll
    for (int m = 0; m < 4; ++m) acc[co][m] = 0.0f;

  for (int ci = 0; ci < CIN; ++ci) {
    float lv[3][6];
#pragma unroll
    for (int dy = 0; dy < 3; ++dy) {
      int yy = y0 + dy - 1;
      bool vy = (unsigned)yy < HWDIM;
      int yc = vy ? yy : 0;
      float4 v = *(const float4*)(inb + (size_t)ci * IMG + yc * HWDIM + x0);
      if (!vy) v = make_float4(0.f, 0.f, 0.f, 0.f);
      float lft = __shfl_up(v.w, 1, 64);
      float rgt = __shfl_down(v.x, 1, 64);
      lv[dy][0] = (x0 == 0) ? 0.0f : lft;
      lv[dy][1] = v.x;
      lv[dy][2] = v.y;
      lv[dy][3] = v.z;
      lv[dy][4] = v.w;
      lv[dy][5] = (x0 == 124) ? 0.0f : rgt;
    }
    const float* wbase = &wlds[ci * 9 * COUT];
#pragma unroll
    for (int dy = 0; dy < 3; ++dy) {
#pragma unroll
      for (int dx = 0; dx < 3; ++dx) {
        const float* wp = wbase + (dy * 3 + dx) * COUT;
        if constexpr (COUT % 4 == 0) {
#pragma unroll
          for (int cg = 0; cg < COUT / 4; ++cg) {
            float4 wv = *(const float4*)(wp + cg * 4);
#pragma unroll
            for (int m = 0; m < 4; ++m) {
              float xv = lv[dy][dx + m];
              acc[cg * 4 + 0][m] += xv * wv.x;
              acc[cg * 4 + 1][m] += xv * wv.y;
              acc[cg * 4 + 2][m] += xv * wv.z;
              acc[cg * 4 + 3][m] += xv * wv.w;
            }
          }
        } else {
#pragma unroll
          for (int co = 0; co < COUT; ++co) {
            float wv = wp[co];
#pragma unroll
            for (int m = 0; m < 4; ++m) acc[co][m] += lv[dy][dx + m] * wv;
          }
        }
      }
    }
  }

  float* ob = out + (size_t)n * COUT * IMG + y0 * HWDIM + x0;
#pragma unroll
  for (int co = 0; co < COUT; ++co) {
    float bv = bias[co];
    float4 o;
    o.x = acc[co][0] + bv;
    o.y = acc[co][1] + bv;
    o.z = acc[co][2] + bv;
    o.w = acc[co][3] + bv;
    if (RELU) {
      o.x = fmaxf(o.x, 0.f);
      o.y = fmaxf(o.y, 0.f);
      o.z = fmaxf(o.z, 0.f);
      o.w = fmaxf(o.w, 0.f);
    }
    *(float4*)(ob + (size_t)co * IMG) = o;
  }
}

// ---------------------------------------------------------------------------
// small utility kernels
// ---------------------------------------------------------------------------
__global__ void zero_int_kernel(int* __restrict__ p, int n) {
  int t = blockIdx.x * blockDim.x + threadIdx.x;
  if (t < n) p[t] = 0;
}

__global__ void hist_kernel(const int* __restrict__ ei, int* __restrict__ hist) {
  int e = blockIdx.x * blockDim.x + threadIdx.x;
  if (e < N_EDGES) atomicAdd(&hist[ei[N_EDGES + e]], 1);
}

// single-block scan over N=50000: row_ptr[0]=0; row_ptr[i+1]=incl_prefix(hist)[i]
__global__ __launch_bounds__(1024) void scan_kernel(const int* __restrict__ hist,
                                                    int* __restrict__ row_ptr, int n) {
  __shared__ int buf[1024];
  __shared__ int carry_s;
  if (threadIdx.x == 0) {
    row_ptr[0] = 0;
    carry_s = 0;
  }
  __syncthreads();
  for (int base = 0; base < n; base += 1024) {
    int idx = base + threadIdx.x;
    int v = (idx < n) ? hist[idx] : 0;
    buf[threadIdx.x] = v;
    __syncthreads();
    for (int off = 1; off < 1024; off <<= 1) {
      int tv = (threadIdx.x >= off) ? buf[threadIdx.x - off] : 0;
      __syncthreads();
      buf[threadIdx.x] += tv;
      __syncthreads();
    }
    int carry = carry_s;
    if (idx < n) row_ptr[idx + 1] = carry + buf[threadIdx.x];
    int total = buf[1023];
    __syncthreads();
    if (threadIdx.x == 0) carry_s = carry + total;
    __syncthreads();
  }
}

__global__ void copy_int_kernel(const int* __restrict__ src, int* __restrict__ dst, int n) {
  int t = blockIdx.x * blockDim.x + threadIdx.x;
  if (t < n) dst[t] = src[t];
}

__global__ void scatter_kernel(const int* __restrict__ ei, int* __restrict__ cursor,
                               int* __restrict__ csr) {
  int e = blockIdx.x * blockDim.x + threadIdx.x;
  if (e < N_EDGES) {
    int d = ei[N_EDGES + e];
    int p = atomicAdd(&cursor[d], 1);
    csr[p] = ei[e];
  }
}

// ---------------------------------------------------------------------------
// gather node features: gx = [x0, x1, x5, x6, x7, pos0, pos1, cnng]
// ---------------------------------------------------------------------------
__global__ void gather_gx_kernel(const float* __restrict__ x, const float* __restrict__ pos,
                                 const int* __restrict__ batch, const float* __restrict__ x1,
                                 float* __restrict__ gx) {
  int t = blockIdx.x * blockDim.x + threadIdx.x;
  if (t >= N_NODES) return;
  float px = pos[2 * t + 0];
  float py = pos[2 * t + 1];
  float fx = px / 20.0f * 127.0f;
  float fy = py / 20.0f * 127.0f;
  int cx = (int)rintf(fx);
  int cy = (int)rintf(fy);
  cx = min(max(cx, 0), HWDIM - 1);
  cy = min(max(cy, 0), HWDIM - 1);
  int b = batch[t];
  float cn = x1[(size_t)b * IMG + cy * HWDIM + cx];
  const float* xr = x + (size_t)t * 8;
  float* g = gx + (size_t)t * 8;
  g[0] = xr[0];
  g[1] = xr[1];
  g[2] = xr[5];
  g[3] = xr[6];
  g[4] = xr[7];
  g[5] = px;
  g[6] = py;
  g[7] = cn;
}

// ---------------------------------------------------------------------------
// CSR aggregation, C=8: 8 lanes per node
// ---------------------------------------------------------------------------
__global__ void agg8_kernel(const float* __restrict__ gx, const int* __restrict__ row_ptr,
                            const int* __restrict__ csr, float* __restrict__ out) {
  int t = blockIdx.x * blockDim.x + threadIdx.x;
  int i = t >> 3;
  int f = t & 7;
  if (i >= N_NODES) return;
  int beg = row_ptr[i], end = row_ptr[i + 1];
  float acc = 0.0f;
  for (int k = beg; k < end; ++k) acc += gx[(size_t)csr[k] * 8 + f];
  out[(size_t)i * 8 + f] = acc / fmaxf((float)(end - beg), 1.0f);
}

// CSR aggregation, C=128: one wave per node, float2 per lane
__global__ __launch_bounds__(256) void agg128_kernel(const float* __restrict__ h,
                                                     const int* __restrict__ row_ptr,
                                                     const int* __restrict__ csr,
                                                     float* __restrict__ out) {
  int wid = (blockIdx.x * blockDim.x + threadIdx.x) >> 6;
  int lane = threadIdx.x & 63;
  if (wid >= N_NODES) return;
  int beg = row_ptr[wid], end = row_ptr[wid + 1];
  float ax = 0.0f, ay = 0.0f;
  const float* hp = h + 2 * lane;
  for (int k = beg; k < end; ++k) {
    int s = csr[k];
    float2 v = *(const float2*)(hp + (size_t)s * HID);
    ax += v.x;
    ay += v.y;
  }
  float inv = 1.0f / fmaxf((float)(end - beg), 1.0f);
  float2 o;
  o.x = ax * inv;
  o.y = ay * inv;
  *(float2*)(out + (size_t)wid * HID + 2 * lane) = o;
}

// ---------------------------------------------------------------------------
// layer1: out[i][j] = relu( sum_k agg8[i][k]*Wl[j][k] + gx[i][k]*Wr[j][k] + b[j] )
// ---------------------------------------------------------------------------
__global__ __launch_bounds__(256) void layer1_kernel(const float* __restrict__ agg8,
                                                     const float* __restrict__ gx,
                                                     const float* __restrict__ Wl,
                                                     const float* __restrict__ Wr,
                                                     const float* __restrict__ b,
                                                     float* __restrict__ out) {
  __shared__ float wl[8][128];
  __shared__ float wr[8][128];
  for (int t = threadIdx.x; t < 1024; t += 256) {
    int j = t >> 3, k = t & 7;
    wl[k][j] = Wl[t];
    wr[k][j] = Wr[t];
  }
  __syncthreads();
  int t = blockIdx.x * blockDim.x + threadIdx.x;
  int i = t >> 7;
  int j = t & 127;
  if (i >= N_NODES) return;
  const float* a = agg8 + (size_t)i * 8;
  const float* g = gx + (size_t)i * 8;
  float acc = b[j];
#pragma unroll
  for (int k = 0; k < 8; ++k) acc += a[k] * wl[k][j] + g[k] * wr[k][j];
  out[(size_t)i * HID + j] = fmaxf(acc, 0.0f);
}

// ---------------------------------------------------------------------------
// fused SAGE GEMM: C[i][j] = act( sum_k A1[i][k]*W1[j][k] + A2[i][k]*W2[j][k] + b[j] )
// 64x64 tile, BK=16, 256 threads, 4x4 microtile.
// ---------------------------------------------------------------------------
__global__ __launch_bounds__(256) void sage_gemm_kernel(
    const float* __restrict__ A1, const float* __restrict__ A2,
    const float* __restrict__ W1, const float* __restrict__ W2,
    const float* __restrict__ bias, float* __restrict__ C, int M, int do_relu) {
  __shared__ float As[16][68];
  __shared__ float Bs[16][68];
  int tid = threadIdx.x;
  int tx = tid & 15;
  int ty = tid >> 4;
  int row0 = blockIdx.x * 64;
  int col0 = blockIdx.y * 64;
  float acc[4][4] = {};
  for (int ks = 0; ks < 16; ++ks) {
    const float* A = (ks < 8) ? A1 : A2;
    const float* W = (ks < 8) ? W1 : W2;
    int k0 = (ks & 7) * 16;
    {
      int r = tid >> 2, seg = tid & 3;
      int gr = row0 + r;
      float4 v = make_float4(0.f, 0.f, 0.f, 0.f);
      if (gr < M) v = *(const float4*)(A + (size_t)gr * HID + k0 + seg * 4);
      As[seg * 4 + 0][r] = v.x;
      As[seg * 4 + 1][r] = v.y;
      As[seg * 4 + 2][r] = v.z;
      As[seg * 4 + 3][r] = v.w;
    }
    {
      int j = tid >> 2, seg = tid & 3;
      int gj = col0 + j;
      float4 v = *(const float4*)(W + (size_t)gj * HID + k0 + seg * 4);
      Bs[seg * 4 + 0][j] = v.x;
      Bs[seg * 4 + 1][j] = v.y;
      Bs[seg * 4 + 2][j] = v.z;
      Bs[seg * 4 + 3][j] = v.w;
    }
    __syncthreads();
#pragma unroll
    for (int kk = 0; kk < 16; ++kk) {
      float a[4], b[4];
#pragma unroll
      for (int m = 0; m < 4; ++m) a[m] = As[kk][ty * 4 + m];
#pragma unroll
      for (int n = 0; n < 4; ++n) b[n] = Bs[kk][tx * 4 + n];
#pragma unroll
      for (int m = 0; m < 4; ++m)
#pragma unroll
        for (int n = 0; n < 4; ++n) acc[m][n] += a[m] * b[n];
    }
    __syncthreads();
  }
#pragma unroll
  for (int m = 0; m < 4; ++m) {
    int gi = row0 + ty * 4 + m;
    if (gi >= M) continue;
#pragma unroll
    for (int n = 0; n < 4; ++n) {
      int gj = col0 + tx * 4 + n;
      float v = acc[m][n] + bias[gj];
      if (do_relu) v = fmaxf(v, 0.0f);
      C[(size_t)gi * HID + gj] = v;
    }
  }
}

// ---------------------------------------------------------------------------
// layer4 projections: z[i] = dot(h[i], Wl4), zr[i] = dot(h[i], Wr4). wave/node.
// ---------------------------------------------------------------------------
__global__ __launch_bounds__(256) void zzr_kernel(const float* __restrict__ h,
                                                  const float* __restrict__ Wl4,
                                                  const float* __restrict__ Wr4,
                                                  float* __restrict__ z,
                                                  float* __restrict__ zr) {
  int wid = (blockIdx.x * blockDim.x + threadIdx.x) >> 6;
  int lane = threadIdx.x & 63;
  if (wid >= N_NODES) return;
  float2 v = *(const float2*)(h + (size_t)wid * HID + 2 * lane);
  float2 wl = *(const float2*)(Wl4 + 2 * lane);
  float2 wr = *(const float2*)(Wr4 + 2 * lane);
  float a = v.x * wl.x + v.y * wl.y;
  float b = v.x * wr.x + v.y * wr.y;
#pragma unroll
  for (int off = 32; off > 0; off >>= 1) {
    a += __shfl_xor(a, off, 64);
    b += __shfl_xor(b, off, 64);
  }
  if (lane == 0) {
    z[wid] = a;
    zr[wid] = b;
  }
}

__global__ void gout_kernel(const float* __restrict__ z, const float* __restrict__ zr,
                            const int* __restrict__ row_ptr, const int* __restrict__ csr,
                            const float* __restrict__ bs4, float* __restrict__ gout) {
  int i = blockIdx.x * blockDim.x + threadIdx.x;
  if (i >= N_NODES) return;
  int beg = row_ptr[i], end = row_ptr[i + 1];
  float s = 0.0f;
  for (int k = beg; k < end; ++k) s += z[csr[k]];
  float d = fmaxf((float)(end - beg), 1.0f);
  gout[i] = s / d + zr[i] + bs4[0];
}

// ---------------------------------------------------------------------------
extern "C" void kernel_launch(void* const* d_in, const int* in_sizes, int n_in,
                              void* d_out, int out_size, void* d_ws, size_t ws_size,
                              hipStream_t stream) {
  const float* xdata = (const float*)d_in[0];
  const float* x = (const float*)d_in[1];
  const float* pos = (const float*)d_in[2];
  const int* ei = (const int*)d_in[3];
  const int* batch = (const int*)d_in[4];
  const float* w1 = (const float*)d_in[5];
  const float* b1 = (const float*)d_in[6];
  const float* w2 = (const float*)d_in[7];
  const float* b2 = (const float*)d_in[8];
  const float* w3 = (const float*)d_in[9];
  const float* b3 = (const float*)d_in[10];
  const float* Wl1 = (const float*)d_in[11];
  const float* Wr1 = (const float*)d_in[12];
  const float* bs1 = (const float*)d_in[13];
  const float* Wl2 = (const float*)d_in[14];
  const float* Wr2 = (const float*)d_in[15];
  const float* bs2 = (const float*)d_in[16];
  const float* Wl3 = (const float*)d_in[17];
  const float* Wr3 = (const float*)d_in[18];
  const float* bs3 = (const float*)d_in[19];
  const float* Wl4 = (const float*)d_in[20];
  const float* Wr4 = (const float*)d_in[21];
  const float* bs4 = (const float*)d_in[22];

  float* x1_out = (float*)d_out;                       // 32*1*128*128
  float* gout = (float*)d_out + (size_t)NBATCH * IMG;  // N

  char* ws = (char*)d_ws;
  size_t off = 0;
  auto take = [&](size_t bytes) -> char* {
    char* p = ws + off;
    off = (off + bytes + 255) & ~(size_t)255;
    return p;
  };
  float* hbuf1 = (float*)take((size_t)NBATCH * 16 * IMG * 4);  // conv h1 / sage h_a
  float* hbuf2 = (float*)take((size_t)NBATCH * 16 * IMG * 4);  // conv h2 / sage h_b
  float* agg = (float*)take((size_t)N_NODES * HID * 4);
  float* gx = (float*)take((size_t)N_NODES * 8 * 4);
  int* hist = (int*)take((size_t)N_NODES * 4);
  int* row_ptr = (int*)take((size_t)(N_NODES + 1) * 4);
  int* cursor = (int*)take((size_t)N_NODES * 4);
  int* csr = (int*)take((size_t)N_EDGES * 4);
  float* z = (float*)take((size_t)N_NODES * 4);
  float* zr = (float*)take((size_t)N_NODES * 4);
  (void)ws_size;

  const int nblk_n = (N_NODES + 255) / 256;
  const int nblk_e = (N_EDGES + 255) / 256;
  const int nblk_conv = NBATCH * 16;  // 512 blocks: 8-row strips

  // ---- CNN stack (register-blocked) ----
  hipLaunchKernelGGL((conv3x3_rb_kernel<8, 16, true>), dim3(nblk_conv), dim3(256), 0, stream,
                     xdata, w1, b1, hbuf1);
  hipLaunchKernelGGL((conv3x3_rb_kernel<16, 16, true>), dim3(nblk_conv), dim3(256), 0, stream,
                     hbuf1, w2, b2, hbuf2);
  hipLaunchKernelGGL((conv3x3_rb_kernel<16, 1, false>), dim3(nblk_conv), dim3(256), 0, stream,
                     hbuf2, w3, b3, x1_out);

  // ---- CSR build ----
  hipLaunchKernelGGL(zero_int_kernel, dim3(nblk_n), dim3(256), 0, stream, hist, N_NODES);
  hipLaunchKernelGGL(hist_kernel, dim3(nblk_e), dim3(256), 0, stream, ei, hist);
  hipLaunchKernelGGL(scan_kernel, dim3(1), dim3(1024), 0, stream, hist, row_ptr, N_NODES);
  hipLaunchKernelGGL(copy_int_kernel, dim3(nblk_n), dim3(256), 0, stream, row_ptr, cursor,
                     N_NODES);
  hipLaunchKernelGGL(scatter_kernel, dim3(nblk_e), dim3(256), 0, stream, ei, cursor, csr);

  // ---- node features ----
  hipLaunchKernelGGL(gather_gx_kernel, dim3(nblk_n), dim3(256), 0, stream, x, pos, batch,
                     x1_out, gx);

  // ---- layer 1 (K=8) ----
  hipLaunchKernelGGL(agg8_kernel, dim3((N_NODES * 8 + 255) / 256), dim3(256), 0, stream, gx,
                     row_ptr, csr, agg);
  hipLaunchKernelGGL(layer1_kernel, dim3((N_NODES * 128) / 256), dim3(256), 0, stream, agg, gx,
                     Wl1, Wr1, bs1, hbuf1);

  // ---- layer 2 ----
  hipLaunchKernelGGL(agg128_kernel, dim3(N_NODES / 4), dim3(256), 0, stream, hbuf1, row_ptr,
                     csr, agg);
  hipLaunchKernelGGL(sage_gemm_kernel, dim3((N_NODES + 63) / 64, 2), dim3(256), 0, stream, agg,
                     hbuf1, Wl2, Wr2, bs2, hbuf2, N_NODES, 1);

  // ---- layer 3 ----
  hipLaunchKernelGGL(agg128_kernel, dim3(N_NODES / 4), dim3(256), 0, stream, hbuf2, row_ptr,
                     csr, agg);
  hipLaunchKernelGGL(sage_gemm_kernel, dim3((N_NODES + 63) / 64, 2), dim3(256), 0, stream, agg,
                     hbuf2, Wl3, Wr3, bs3, hbuf1, N_NODES, 1);

  // ---- layer 4 (project to scalar first, then aggregate scalars) ----
  hipLaunchKernelGGL(zzr_kernel, dim3(N_NODES / 4), dim3(256), 0, stream, hbuf1, Wl4, Wr4, z,
                     zr);
  hipLaunchKernelGGL(gout_kernel, dim3(nblk_n), dim3(256), 0, stream, z, zr, row_ptr, csr, bs4,
                     gout);
}

// Round 3
// 447.371 us; speedup vs baseline: 2.5911x; 1.3259x over previous
//
#include <hip/hip_runtime.h>

#define N_NODES 50000
#define N_EDGES 800000
#define NBATCH 32
#define HWDIM 128
#define IMG (HWDIM * HWDIM)
#define HID 128
#define SCAN_BLK 1024
#define NSCAN ((N_NODES + SCAN_BLK - 1) / SCAN_BLK)  // 49

// ---------------------------------------------------------------------------
// Register-blocked conv 3x3 SAME, NCHW. 256 thr = 8 rows x 32; 4 px/thread.
// ---------------------------------------------------------------------------
template <int CIN, int COUT, bool RELU>
__global__ __launch_bounds__(256) void conv3x3_rb_kernel(
    const float* __restrict__ in, const float* __restrict__ w,
    const float* __restrict__ bias, float* __restrict__ out) {
  __shared__ float wlds[CIN * 9 * COUT];
  for (int idx = threadIdx.x; idx < CIN * COUT * 9; idx += 256) {
    int co = idx / (CIN * 9);
    int r = idx - co * CIN * 9;
    int ci = r / 9;
    int tap = r - ci * 9;
    wlds[(ci * 9 + tap) * COUT + co] = w[idx];
  }
  __syncthreads();

  int n = blockIdx.x >> 4;
  int strip = blockIdx.x & 15;
  int y0 = strip * 8 + (threadIdx.x >> 5);
  int x0 = (threadIdx.x & 31) * 4;
  const float* inb = in + (size_t)n * CIN * IMG;

  float acc[COUT][4];
#pragma unroll
  for (int co = 0; co < COUT; ++co)
#pragma unroll
    for (int m = 0; m < 4; ++m) acc[co][m] = 0.0f;

  for (int ci = 0; ci < CIN; ++ci) {
    float lv[3][6];
#pragma unroll
    for (int dy = 0; dy < 3; ++dy) {
      int yy = y0 + dy - 1;
      bool vy = (unsigned)yy < HWDIM;
      int yc = vy ? yy : 0;
      float4 v = *(const float4*)(inb + (size_t)ci * IMG + yc * HWDIM + x0);
      if (!vy) v = make_float4(0.f, 0.f, 0.f, 0.f);
      float lft = __shfl_up(v.w, 1, 64);
      float rgt = __shfl_down(v.x, 1, 64);
      lv[dy][0] = (x0 == 0) ? 0.0f : lft;
      lv[dy][1] = v.x;
      lv[dy][2] = v.y;
      lv[dy][3] = v.z;
      lv[dy][4] = v.w;
      lv[dy][5] = (x0 == 124) ? 0.0f : rgt;
    }
    const float* wbase = &wlds[ci * 9 * COUT];
#pragma unroll
    for (int dy = 0; dy < 3; ++dy) {
#pragma unroll
      for (int dx = 0; dx < 3; ++dx) {
        const float* wp = wbase + (dy * 3 + dx) * COUT;
        if constexpr (COUT % 4 == 0) {
#pragma unroll
          for (int cg = 0; cg < COUT / 4; ++cg) {
            float4 wv = *(const float4*)(wp + cg * 4);
#pragma unroll
            for (int m = 0; m < 4; ++m) {
              float xv = lv[dy][dx + m];
              acc[cg * 4 + 0][m] += xv * wv.x;
              acc[cg * 4 + 1][m] += xv * wv.y;
              acc[cg * 4 + 2][m] += xv * wv.z;
              acc[cg * 4 + 3][m] += xv * wv.w;
            }
          }
        } else {
#pragma unroll
          for (int co = 0; co < COUT; ++co) {
            float wv = wp[co];
#pragma unroll
            for (int m = 0; m < 4; ++m) acc[co][m] += lv[dy][dx + m] * wv;
          }
        }
      }
    }
  }

  float* ob = out + (size_t)n * COUT * IMG + y0 * HWDIM + x0;
#pragma unroll
  for (int co = 0; co < COUT; ++co) {
    float bv = bias[co];
    float4 o;
    o.x = acc[co][0] + bv;
    o.y = acc[co][1] + bv;
    o.z = acc[co][2] + bv;
    o.w = acc[co][3] + bv;
    if (RELU) {
      o.x = fmaxf(o.x, 0.f);
      o.y = fmaxf(o.y, 0.f);
      o.z = fmaxf(o.z, 0.f);
      o.w = fmaxf(o.w, 0.f);
    }
    *(float4*)(ob + (size_t)co * IMG) = o;
  }
}

// ---------------------------------------------------------------------------
// CSR build helpers
// ---------------------------------------------------------------------------
__global__ void zero_int_kernel(int* __restrict__ p, int n) {
  int t = blockIdx.x * blockDim.x + threadIdx.x;
  if (t < n) p[t] = 0;
}

__global__ void hist_kernel(const int* __restrict__ ei, int* __restrict__ hist) {
  int e = blockIdx.x * blockDim.x + threadIdx.x;
  if (e < N_EDGES) atomicAdd(&hist[ei[N_EDGES + e]], 1);
}

// phase A: per-block inclusive scan (1024 elems) -> scanbuf, block totals -> partials
__global__ __launch_bounds__(1024) void scan_local_kernel(const int* __restrict__ hist,
                                                          int* __restrict__ scanbuf,
                                                          int* __restrict__ partials) {
  __shared__ int wsum[16];
  int t = threadIdx.x;
  int idx = blockIdx.x * SCAN_BLK + t;
  int lane = t & 63, w = t >> 6;
  int v = (idx < N_NODES) ? hist[idx] : 0;
  int s = v;
#pragma unroll
  for (int off = 1; off < 64; off <<= 1) {
    int u = __shfl_up(s, off, 64);
    if (lane >= off) s += u;
  }
  if (lane == 63) wsum[w] = s;
  __syncthreads();
  if (w == 0 && lane < 16) {
    int ws = wsum[lane];
#pragma unroll
    for (int off = 1; off < 16; off <<= 1) {
      int u = __shfl_up(ws, off, 64);
      if (lane >= off) ws += u;
    }
    wsum[lane] = ws;
  }
  __syncthreads();
  int base = (w > 0) ? wsum[w - 1] : 0;
  s += base;
  if (idx < N_NODES) scanbuf[idx] = s;
  if (t == SCAN_BLK - 1) partials[blockIdx.x] = s;
}

// phase B: exclusive scan of NSCAN (<=64) partials in one wave, in place
__global__ void scan_partials_kernel(int* __restrict__ partials) {
  int lane = threadIdx.x;
  int v = (lane < NSCAN) ? partials[lane] : 0;
  int s = v;
#pragma unroll
  for (int off = 1; off < 64; off <<= 1) {
    int u = __shfl_up(s, off, 64);
    if (lane >= off) s += u;
  }
  if (lane < NSCAN) partials[lane] = s - v;
}

// phase C: row_ptr[idx+1] = scanbuf[idx] + partials[idx/1024]; also init cursor
__global__ void scan_add_kernel(const int* __restrict__ scanbuf,
                                const int* __restrict__ partials,
                                int* __restrict__ row_ptr, int* __restrict__ cursor) {
  int idx = blockIdx.x * blockDim.x + threadIdx.x;
  if (idx == 0) {
    row_ptr[0] = 0;
    cursor[0] = 0;
  }
  if (idx < N_NODES) {
    int val = scanbuf[idx] + partials[idx >> 10];
    row_ptr[idx + 1] = val;
    if (idx + 1 < N_NODES) cursor[idx + 1] = val;
  }
}

__global__ void scatter_kernel(const int* __restrict__ ei, int* __restrict__ cursor,
                               int* __restrict__ csr) {
  int e = blockIdx.x * blockDim.x + threadIdx.x;
  if (e < N_EDGES) {
    int d = ei[N_EDGES + e];
    int p = atomicAdd(&cursor[d], 1);
    csr[p] = ei[e];
  }
}

// ---------------------------------------------------------------------------
// gather node features: gx = [x0, x1, x5, x6, x7, pos0, pos1, cnng]
// ---------------------------------------------------------------------------
__global__ void gather_gx_kernel(const float* __restrict__ x, const float* __restrict__ pos,
                                 const int* __restrict__ batch, const float* __restrict__ x1,
                                 float* __restrict__ gx) {
  int t = blockIdx.x * blockDim.x + threadIdx.x;
  if (t >= N_NODES) return;
  float px = pos[2 * t + 0];
  float py = pos[2 * t + 1];
  float fx = px / 20.0f * 127.0f;
  float fy = py / 20.0f * 127.0f;
  int cx = (int)rintf(fx);
  int cy = (int)rintf(fy);
  cx = min(max(cx, 0), HWDIM - 1);
  cy = min(max(cy, 0), HWDIM - 1);
  int b = batch[t];
  float cn = x1[(size_t)b * IMG + cy * HWDIM + cx];
  const float* xr = x + (size_t)t * 8;
  float* g = gx + (size_t)t * 8;
  g[0] = xr[0];
  g[1] = xr[1];
  g[2] = xr[5];
  g[3] = xr[6];
  g[4] = xr[7];
  g[5] = px;
  g[6] = py;
  g[7] = cn;
}

// ---------------------------------------------------------------------------
// CSR aggregation, C=8: 8 lanes per node
// ---------------------------------------------------------------------------
__global__ void agg8_kernel(const float* __restrict__ gx, const int* __restrict__ row_ptr,
                            const int* __restrict__ csr, float* __restrict__ out) {
  int t = blockIdx.x * blockDim.x + threadIdx.x;
  int i = t >> 3;
  int f = t & 7;
  if (i >= N_NODES) return;
  int beg = row_ptr[i], end = row_ptr[i + 1];
  float acc = 0.0f;
  int k = beg;
  for (; k + 2 <= end; k += 2) {
    int s0 = csr[k], s1 = csr[k + 1];
    acc += gx[(size_t)s0 * 8 + f] + gx[(size_t)s1 * 8 + f];
  }
  for (; k < end; ++k) acc += gx[(size_t)csr[k] * 8 + f];
  out[(size_t)i * 8 + f] = acc / fmaxf((float)(end - beg), 1.0f);
}

// ---------------------------------------------------------------------------
// CSR aggregation, C=128: one wave per node, float2/lane, 4x unrolled with
// scalar-path index loads (readfirstlane forces SGPR loop bounds).
// ---------------------------------------------------------------------------
__global__ __launch_bounds__(256) void agg128_kernel(const float* __restrict__ h,
                                                     const int* __restrict__ row_ptr,
                                                     const int* __restrict__ csr,
                                                     float* __restrict__ out) {
  int wid = (blockIdx.x * blockDim.x + threadIdx.x) >> 6;
  int lane = threadIdx.x & 63;
  if (wid >= N_NODES) return;
  int beg = __builtin_amdgcn_readfirstlane(row_ptr[wid]);
  int end = __builtin_amdgcn_readfirstlane(row_ptr[wid + 1]);
  float ax = 0.0f, ay = 0.0f;
  const float* hp = h + 2 * lane;
  int k = beg;
  for (; k + 4 <= end; k += 4) {
    int s0 = csr[k];
    int s1 = csr[k + 1];
    int s2 = csr[k + 2];
    int s3 = csr[k + 3];
    float2 v0 = *(const float2*)(hp + (size_t)s0 * HID);
    float2 v1 = *(const float2*)(hp + (size_t)s1 * HID);
    float2 v2 = *(const float2*)(hp + (size_t)s2 * HID);
    float2 v3 = *(const float2*)(hp + (size_t)s3 * HID);
    ax += (v0.x + v1.x) + (v2.x + v3.x);
    ay += (v0.y + v1.y) + (v2.y + v3.y);
  }
  for (; k < end; ++k) {
    int s = csr[k];
    float2 v = *(const float2*)(hp + (size_t)s * HID);
    ax += v.x;
    ay += v.y;
  }
  float inv = 1.0f / fmaxf((float)(end - beg), 1.0f);
  float2 o;
  o.x = ax * inv;
  o.y = ay * inv;
  *(float2*)(out + (size_t)wid * HID + 2 * lane) = o;
}

// ---------------------------------------------------------------------------
// layer1: out[i][j] = relu( sum_k agg8[i][k]*Wl[j][k] + gx[i][k]*Wr[j][k] + b[j] )
// ---------------------------------------------------------------------------
__global__ __launch_bounds__(256) void layer1_kernel(const float* __restrict__ agg8,
                                                     const float* __restrict__ gx,
                                                     const float* __restrict__ Wl,
                                                     const float* __restrict__ Wr,
                                                     const float* __restrict__ b,
                                                     float* __restrict__ out) {
  __shared__ float wl[8][128];
  __shared__ float wr[8][128];
  for (int t = threadIdx.x; t < 1024; t += 256) {
    int j = t >> 3, k = t & 7;
    wl[k][j] = Wl[t];
    wr[k][j] = Wr[t];
  }
  __syncthreads();
  int t = blockIdx.x * blockDim.x + threadIdx.x;
  int i = t >> 7;
  int j = t & 127;
  if (i >= N_NODES) return;
  const float* a = agg8 + (size_t)i * 8;
  const float* g = gx + (size_t)i * 8;
  float acc = b[j];
#pragma unroll
  for (int k = 0; k < 8; ++k) acc += a[k] * wl[k][j] + g[k] * wr[k][j];
  out[(size_t)i * HID + j] = fmaxf(acc, 0.0f);
}

// ---------------------------------------------------------------------------
// fused SAGE GEMM: C[i][j] = act( sum_k A1[i][k]*W1[j][k] + A2[i][k]*W2[j][k] + b[j] )
// ---------------------------------------------------------------------------
__global__ __launch_bounds__(256) void sage_gemm_kernel(
    const float* __restrict__ A1, const float* __restrict__ A2,
    const float* __restrict__ W1, const float* __restrict__ W2,
    const float* __restrict__ bias, float* __restrict__ C, int M, int do_relu) {
  __shared__ float As[16][68];
  __shared__ float Bs[16][68];
  int tid = threadIdx.x;
  int tx = tid & 15;
  int ty = tid >> 4;
  int row0 = blockIdx.x * 64;
  int col0 = blockIdx.y * 64;
  float acc[4][4] = {};
  for (int ks = 0; ks < 16; ++ks) {
    const float* A = (ks < 8) ? A1 : A2;
    const float* W = (ks < 8) ? W1 : W2;
    int k0 = (ks & 7) * 16;
    {
      int r = tid >> 2, seg = tid & 3;
      int gr = row0 + r;
      float4 v = make_float4(0.f, 0.f, 0.f, 0.f);
      if (gr < M) v = *(const float4*)(A + (size_t)gr * HID + k0 + seg * 4);
      As[seg * 4 + 0][r] = v.x;
      As[seg * 4 + 1][r] = v.y;
      As[seg * 4 + 2][r] = v.z;
      As[seg * 4 + 3][r] = v.w;
    }
    {
      int j = tid >> 2, seg = tid & 3;
      int gj = col0 + j;
      float4 v = *(const float4*)(W + (size_t)gj * HID + k0 + seg * 4);
      Bs[seg * 4 + 0][j] = v.x;
      Bs[seg * 4 + 1][j] = v.y;
      Bs[seg * 4 + 2][j] = v.z;
      Bs[seg * 4 + 3][j] = v.w;
    }
    __syncthreads();
#pragma unroll
    for (int kk = 0; kk < 16; ++kk) {
      float a[4], b[4];
#pragma unroll
      for (int m = 0; m < 4; ++m) a[m] = As[kk][ty * 4 + m];
#pragma unroll
      for (int n = 0; n < 4; ++n) b[n] = Bs[kk][tx * 4 + n];
#pragma unroll
      for (int m = 0; m < 4; ++m)
#pragma unroll
        for (int n = 0; n < 4; ++n) acc[m][n] += a[m] * b[n];
    }
    __syncthreads();
  }
#pragma unroll
  for (int m = 0; m < 4; ++m) {
    int gi = row0 + ty * 4 + m;
    if (gi >= M) continue;
#pragma unroll
    for (int n = 0; n < 4; ++n) {
      int gj = col0 + tx * 4 + n;
      float v = acc[m][n] + bias[gj];
      if (do_relu) v = fmaxf(v, 0.0f);
      C[(size_t)gi * HID + gj] = v;
    }
  }
}

// ---------------------------------------------------------------------------
// layer4 projections + scalar aggregation
// ---------------------------------------------------------------------------
__global__ __launch_bounds__(256) void zzr_kernel(const float* __restrict__ h,
                                                  const float* __restrict__ Wl4,
                                                  const float* __restrict__ Wr4,
                                                  float* __restrict__ z,
                                                  float* __restrict__ zr) {
  int wid = (blockIdx.x * blockDim.x + threadIdx.x) >> 6;
  int lane = threadIdx.x & 63;
  if (wid >= N_NODES) return;
  float2 v = *(const float2*)(h + (size_t)wid * HID + 2 * lane);
  float2 wl = *(const float2*)(Wl4 + 2 * lane);
  float2 wr = *(const float2*)(Wr4 + 2 * lane);
  float a = v.x * wl.x + v.y * wl.y;
  float b = v.x * wr.x + v.y * wr.y;
#pragma unroll
  for (int off = 32; off > 0; off >>= 1) {
    a += __shfl_xor(a, off, 64);
    b += __shfl_xor(b, off, 64);
  }
  if (lane == 0) {
    z[wid] = a;
    zr[wid] = b;
  }
}

__global__ void gout_kernel(const float* __restrict__ z, const float* __restrict__ zr,
                            const int* __restrict__ row_ptr, const int* __restrict__ csr,
                            const float* __restrict__ bs4, float* __restrict__ gout) {
  int i = blockIdx.x * blockDim.x + threadIdx.x;
  if (i >= N_NODES) return;
  int beg = row_ptr[i], end = row_ptr[i + 1];
  float s = 0.0f;
  int k = beg;
  for (; k + 2 <= end; k += 2) s += z[csr[k]] + z[csr[k + 1]];
  for (; k < end; ++k) s += z[csr[k]];
  float d = fmaxf((float)(end - beg), 1.0f);
  gout[i] = s / d + zr[i] + bs4[0];
}

// ---------------------------------------------------------------------------
extern "C" void kernel_launch(void* const* d_in, const int* in_sizes, int n_in,
                              void* d_out, int out_size, void* d_ws, size_t ws_size,
                              hipStream_t stream) {
  const float* xdata = (const float*)d_in[0];
  const float* x = (const float*)d_in[1];
  const float* pos = (const float*)d_in[2];
  const int* ei = (const int*)d_in[3];
  const int* batch = (const int*)d_in[4];
  const float* w1 = (const float*)d_in[5];
  const float* b1 = (const float*)d_in[6];
  const float* w2 = (const float*)d_in[7];
  const float* b2 = (const float*)d_in[8];
  const float* w3 = (const float*)d_in[9];
  const float* b3 = (const float*)d_in[10];
  const float* Wl1 = (const float*)d_in[11];
  const float* Wr1 = (const float*)d_in[12];
  const float* bs1 = (const float*)d_in[13];
  const float* Wl2 = (const float*)d_in[14];
  const float* Wr2 = (const float*)d_in[15];
  const float* bs2 = (const float*)d_in[16];
  const float* Wl3 = (const float*)d_in[17];
  const float* Wr3 = (const float*)d_in[18];
  const float* bs3 = (const float*)d_in[19];
  const float* Wl4 = (const float*)d_in[20];
  const float* Wr4 = (const float*)d_in[21];
  const float* bs4 = (const float*)d_in[22];

  float* x1_out = (float*)d_out;                       // 32*1*128*128
  float* gout = (float*)d_out + (size_t)NBATCH * IMG;  // N

  char* ws = (char*)d_ws;
  size_t off = 0;
  auto take = [&](size_t bytes) -> char* {
    char* p = ws + off;
    off = (off + bytes + 255) & ~(size_t)255;
    return p;
  };
  float* hbuf1 = (float*)take((size_t)NBATCH * 16 * IMG * 4);  // conv h1 / sage h_a
  float* hbuf2 = (float*)take((size_t)NBATCH * 16 * IMG * 4);  // conv h2 / sage h_b
  float* agg = (float*)take((size_t)N_NODES * HID * 4);
  float* gx = (float*)take((size_t)N_NODES * 8 * 4);
  int* hist = (int*)take((size_t)N_NODES * 4);
  int* scanbuf = (int*)take((size_t)N_NODES * 4);
  int* partials = (int*)take((size_t)NSCAN * 4);
  int* row_ptr = (int*)take((size_t)(N_NODES + 1) * 4);
  int* cursor = (int*)take((size_t)N_NODES * 4);
  int* csr = (int*)take((size_t)N_EDGES * 4);
  float* z = (float*)take((size_t)N_NODES * 4);
  float* zr = (float*)take((size_t)N_NODES * 4);
  (void)ws_size;

  const int nblk_n = (N_NODES + 255) / 256;
  const int nblk_e = (N_EDGES + 255) / 256;
  const int nblk_conv = NBATCH * 16;  // 512 blocks: 8-row strips

  // ---- CNN stack (register-blocked) ----
  hipLaunchKernelGGL((conv3x3_rb_kernel<8, 16, true>), dim3(nblk_conv), dim3(256), 0, stream,
                     xdata, w1, b1, hbuf1);
  hipLaunchKernelGGL((conv3x3_rb_kernel<16, 16, true>), dim3(nblk_conv), dim3(256), 0, stream,
                     hbuf1, w2, b2, hbuf2);
  hipLaunchKernelGGL((conv3x3_rb_kernel<16, 1, false>), dim3(nblk_conv), dim3(256), 0, stream,
                     hbuf2, w3, b3, x1_out);

  // ---- CSR build (multi-block scan) ----
  hipLaunchKernelGGL(zero_int_kernel, dim3(nblk_n), dim3(256), 0, stream, hist, N_NODES);
  hipLaunchKernelGGL(hist_kernel, dim3(nblk_e), dim3(256), 0, stream, ei, hist);
  hipLaunchKernelGGL(scan_local_kernel, dim3(NSCAN), dim3(SCAN_BLK), 0, stream, hist, scanbuf,
                     partials);
  hipLaunchKernelGGL(scan_partials_kernel, dim3(1), dim3(64), 0, stream, partials);
  hipLaunchKernelGGL(scan_add_kernel, dim3(nblk_n), dim3(256), 0, stream, scanbuf, partials,
                     row_ptr, cursor);
  hipLaunchKernelGGL(scatter_kernel, dim3(nblk_e), dim3(256), 0, stream, ei, cursor, csr);

  // ---- node features ----
  hipLaunchKernelGGL(gather_gx_kernel, dim3(nblk_n), dim3(256), 0, stream, x, pos, batch,
                     x1_out, gx);

  // ---- layer 1 (K=8) ----
  hipLaunchKernelGGL(agg8_kernel, dim3((N_NODES * 8 + 255) / 256), dim3(256), 0, stream, gx,
                     row_ptr, csr, agg);
  hipLaunchKernelGGL(layer1_kernel, dim3((N_NODES * 128) / 256), dim3(256), 0, stream, agg, gx,
                     Wl1, Wr1, bs1, hbuf1);

  // ---- layer 2 ----
  hipLaunchKernelGGL(agg128_kernel, dim3(N_NODES / 4), dim3(256), 0, stream, hbuf1, row_ptr,
                     csr, agg);
  hipLaunchKernelGGL(sage_gemm_kernel, dim3((N_NODES + 63) / 64, 2), dim3(256), 0, stream, agg,
                     hbuf1, Wl2, Wr2, bs2, hbuf2, N_NODES, 1);

  // ---- layer 3 ----
  hipLaunchKernelGGL(agg128_kernel, dim3(N_NODES / 4), dim3(256), 0, stream, hbuf2, row_ptr,
                     csr, agg);
  hipLaunchKernelGGL(sage_gemm_kernel, dim3((N_NODES + 63) / 64, 2), dim3(256), 0, stream, agg,
                     hbuf2, Wl3, Wr3, bs3, hbuf1, N_NODES, 1);

  // ---- layer 4 (project to scalar first, then aggregate scalars) ----
  hipLaunchKernelGGL(zzr_kernel, dim3(N_NODES / 4), dim3(256), 0, stream, hbuf1, Wl4, Wr4, z,
                     zr);
  hipLaunchKernelGGL(gout_kernel, dim3(nblk_n), dim3(256), 0, stream, z, zr, row_ptr, csr, bs4,
                     gout);
}

// Round 4
// 333.372 us; speedup vs baseline: 3.4771x; 1.3420x over previous
//
#include <hip/hip_runtime.h>

#define N_NODES 50000
#define N_EDGES 800000
#define NBATCH 32
#define HWDIM 128
#define IMG (HWDIM * HWDIM)
#define HID 128
#define SCAN_BLK 1024
#define NSCAN ((N_NODES + SCAN_BLK - 1) / SCAN_BLK)  // 49
#define LDSP 40  // padded LDS row stride in bf16 elems (80 B) -> <=2-way conflicts

typedef float f32x4 __attribute__((ext_vector_type(4)));
typedef __bf16 bf16x8 __attribute__((ext_vector_type(8)));
typedef unsigned short u16x8 __attribute__((ext_vector_type(8)));

__device__ __forceinline__ unsigned short f2bf(float x) {
  unsigned u = __builtin_bit_cast(unsigned, x);
  u = (u + 0x7FFF + ((u >> 16) & 1)) >> 16;
  return (unsigned short)u;
}
__device__ __forceinline__ float bf2f(unsigned short h) {
  return __builtin_bit_cast(float, (unsigned)h << 16);
}

// ---------------------------------------------------------------------------
// Register-blocked conv 3x3 SAME, NCHW. 256 thr = 8 rows x 32; 4 px/thread.
// ---------------------------------------------------------------------------
template <int CIN, int COUT, bool RELU>
__global__ __launch_bounds__(256) void conv3x3_rb_kernel(
    const float* __restrict__ in, const float* __restrict__ w,
    const float* __restrict__ bias, float* __restrict__ out) {
  __shared__ float wlds[CIN * 9 * COUT];
  for (int idx = threadIdx.x; idx < CIN * COUT * 9; idx += 256) {
    int co = idx / (CIN * 9);
    int r = idx - co * CIN * 9;
    int ci = r / 9;
    int tap = r - ci * 9;
    wlds[(ci * 9 + tap) * COUT + co] = w[idx];
  }
  __syncthreads();

  int n = blockIdx.x >> 4;
  int strip = blockIdx.x & 15;
  int y0 = strip * 8 + (threadIdx.x >> 5);
  int x0 = (threadIdx.x & 31) * 4;
  const float* inb = in + (size_t)n * CIN * IMG;

  float acc[COUT][4];
#pragma unroll
  for (int co = 0; co < COUT; ++co)
#pragma unroll
    for (int m = 0; m < 4; ++m) acc[co][m] = 0.0f;

  for (int ci = 0; ci < CIN; ++ci) {
    float lv[3][6];
#pragma unroll
    for (int dy = 0; dy < 3; ++dy) {
      int yy = y0 + dy - 1;
      bool vy = (unsigned)yy < HWDIM;
      int yc = vy ? yy : 0;
      float4 v = *(const float4*)(inb + (size_t)ci * IMG + yc * HWDIM + x0);
      if (!vy) v = make_float4(0.f, 0.f, 0.f, 0.f);
      float lft = __shfl_up(v.w, 1, 64);
      float rgt = __shfl_down(v.x, 1, 64);
      lv[dy][0] = (x0 == 0) ? 0.0f : lft;
      lv[dy][1] = v.x;
      lv[dy][2] = v.y;
      lv[dy][3] = v.z;
      lv[dy][4] = v.w;
      lv[dy][5] = (x0 == 124) ? 0.0f : rgt;
    }
    const float* wbase = &wlds[ci * 9 * COUT];
#pragma unroll
    for (int dy = 0; dy < 3; ++dy) {
#pragma unroll
      for (int dx = 0; dx < 3; ++dx) {
        const float* wp = wbase + (dy * 3 + dx) * COUT;
        if constexpr (COUT % 4 == 0) {
#pragma unroll
          for (int cg = 0; cg < COUT / 4; ++cg) {
            float4 wv = *(const float4*)(wp + cg * 4);
#pragma unroll
            for (int m = 0; m < 4; ++m) {
              float xv = lv[dy][dx + m];
              acc[cg * 4 + 0][m] += xv * wv.x;
              acc[cg * 4 + 1][m] += xv * wv.y;
              acc[cg * 4 + 2][m] += xv * wv.z;
              acc[cg * 4 + 3][m] += xv * wv.w;
            }
          }
        } else {
#pragma unroll
          for (int co = 0; co < COUT; ++co) {
            float wv = wp[co];
#pragma unroll
            for (int m = 0; m < 4; ++m) acc[co][m] += lv[dy][dx + m] * wv;
          }
        }
      }
    }
  }

  float* ob = out + (size_t)n * COUT * IMG + y0 * HWDIM + x0;
#pragma unroll
  for (int co = 0; co < COUT; ++co) {
    float bv = bias[co];
    float4 o;
    o.x = acc[co][0] + bv;
    o.y = acc[co][1] + bv;
    o.z = acc[co][2] + bv;
    o.w = acc[co][3] + bv;
    if (RELU) {
      o.x = fmaxf(o.x, 0.f);
      o.y = fmaxf(o.y, 0.f);
      o.z = fmaxf(o.z, 0.f);
      o.w = fmaxf(o.w, 0.f);
    }
    *(float4*)(ob + (size_t)co * IMG) = o;
  }
}

// ---------------------------------------------------------------------------
// CSR build helpers
// ---------------------------------------------------------------------------
__global__ void zero_int_kernel(int* __restrict__ p, int n) {
  int t = blockIdx.x * blockDim.x + threadIdx.x;
  if (t < n) p[t] = 0;
}

__global__ void hist_kernel(const int* __restrict__ ei, int* __restrict__ hist) {
  int e = blockIdx.x * blockDim.x + threadIdx.x;
  if (e < N_EDGES) atomicAdd(&hist[ei[N_EDGES + e]], 1);
}

__global__ __launch_bounds__(1024) void scan_local_kernel(const int* __restrict__ hist,
                                                          int* __restrict__ scanbuf,
                                                          int* __restrict__ partials) {
  __shared__ int wsum[16];
  int t = threadIdx.x;
  int idx = blockIdx.x * SCAN_BLK + t;
  int lane = t & 63, w = t >> 6;
  int v = (idx < N_NODES) ? hist[idx] : 0;
  int s = v;
#pragma unroll
  for (int off = 1; off < 64; off <<= 1) {
    int u = __shfl_up(s, off, 64);
    if (lane >= off) s += u;
  }
  if (lane == 63) wsum[w] = s;
  __syncthreads();
  if (w == 0 && lane < 16) {
    int ws = wsum[lane];
#pragma unroll
    for (int off = 1; off < 16; off <<= 1) {
      int u = __shfl_up(ws, off, 64);
      if (lane >= off) ws += u;
    }
    wsum[lane] = ws;
  }
  __syncthreads();
  int base = (w > 0) ? wsum[w - 1] : 0;
  s += base;
  if (idx < N_NODES) scanbuf[idx] = s;
  if (t == SCAN_BLK - 1) partials[blockIdx.x] = s;
}

__global__ void scan_partials_kernel(int* __restrict__ partials) {
  int lane = threadIdx.x;
  int v = (lane < NSCAN) ? partials[lane] : 0;
  int s = v;
#pragma unroll
  for (int off = 1; off < 64; off <<= 1) {
    int u = __shfl_up(s, off, 64);
    if (lane >= off) s += u;
  }
  if (lane < NSCAN) partials[lane] = s - v;
}

__global__ void scan_add_kernel(const int* __restrict__ scanbuf,
                                const int* __restrict__ partials,
                                int* __restrict__ row_ptr, int* __restrict__ cursor) {
  int idx = blockIdx.x * blockDim.x + threadIdx.x;
  if (idx == 0) {
    row_ptr[0] = 0;
    cursor[0] = 0;
  }
  if (idx < N_NODES) {
    int val = scanbuf[idx] + partials[idx >> 10];
    row_ptr[idx + 1] = val;
    if (idx + 1 < N_NODES) cursor[idx + 1] = val;
  }
}

__global__ void scatter_kernel(const int* __restrict__ ei, int* __restrict__ cursor,
                               int* __restrict__ csr) {
  int e = blockIdx.x * blockDim.x + threadIdx.x;
  if (e < N_EDGES) {
    int d = ei[N_EDGES + e];
    int p = atomicAdd(&cursor[d], 1);
    csr[p] = ei[e];
  }
}

// ---------------------------------------------------------------------------
// gather node features: gx = [x0, x1, x5, x6, x7, pos0, pos1, cnng]
// ---------------------------------------------------------------------------
__global__ void gather_gx_kernel(const float* __restrict__ x, const float* __restrict__ pos,
                                 const int* __restrict__ batch, const float* __restrict__ x1,
                                 float* __restrict__ gx) {
  int t = blockIdx.x * blockDim.x + threadIdx.x;
  if (t >= N_NODES) return;
  float px = pos[2 * t + 0];
  float py = pos[2 * t + 1];
  float fx = px / 20.0f * 127.0f;
  float fy = py / 20.0f * 127.0f;
  int cx = (int)rintf(fx);
  int cy = (int)rintf(fy);
  cx = min(max(cx, 0), HWDIM - 1);
  cy = min(max(cy, 0), HWDIM - 1);
  int b = batch[t];
  float cn = x1[(size_t)b * IMG + cy * HWDIM + cx];
  const float* xr = x + (size_t)t * 8;
  float* g = gx + (size_t)t * 8;
  g[0] = xr[0];
  g[1] = xr[1];
  g[2] = xr[5];
  g[3] = xr[6];
  g[4] = xr[7];
  g[5] = px;
  g[6] = py;
  g[7] = cn;
}

// ---------------------------------------------------------------------------
// CSR aggregation, C=8 (f32 in/out)
// ---------------------------------------------------------------------------
__global__ void agg8_kernel(const float* __restrict__ gx, const int* __restrict__ row_ptr,
                            const int* __restrict__ csr, float* __restrict__ out) {
  int t = blockIdx.x * blockDim.x + threadIdx.x;
  int i = t >> 3;
  int f = t & 7;
  if (i >= N_NODES) return;
  int beg = row_ptr[i], end = row_ptr[i + 1];
  float acc = 0.0f;
  int k = beg;
  for (; k + 2 <= end; k += 2) {
    int s0 = csr[k], s1 = csr[k + 1];
    acc += gx[(size_t)s0 * 8 + f] + gx[(size_t)s1 * 8 + f];
  }
  for (; k < end; ++k) acc += gx[(size_t)csr[k] * 8 + f];
  out[(size_t)i * 8 + f] = acc / fmaxf((float)(end - beg), 1.0f);
}

// ---------------------------------------------------------------------------
// CSR aggregation, C=128, bf16 in/out, f32 accum. One wave/node, uint/lane.
// ---------------------------------------------------------------------------
__global__ __launch_bounds__(256) void agg128_bf16_kernel(
    const unsigned short* __restrict__ h, const int* __restrict__ row_ptr,
    const int* __restrict__ csr, unsigned short* __restrict__ out) {
  int wid = (blockIdx.x * blockDim.x + threadIdx.x) >> 6;
  int lane = threadIdx.x & 63;
  if (wid >= N_NODES) return;
  int beg = __builtin_amdgcn_readfirstlane(row_ptr[wid]);
  int end = __builtin_amdgcn_readfirstlane(row_ptr[wid + 1]);
  float ax = 0.0f, ay = 0.0f;
  const unsigned short* hp = h + 2 * lane;
  int k = beg;
  for (; k + 4 <= end; k += 4) {
    int s0 = csr[k];
    int s1 = csr[k + 1];
    int s2 = csr[k + 2];
    int s3 = csr[k + 3];
    unsigned v0 = *(const unsigned*)(hp + (size_t)s0 * HID);
    unsigned v1 = *(const unsigned*)(hp + (size_t)s1 * HID);
    unsigned v2 = *(const unsigned*)(hp + (size_t)s2 * HID);
    unsigned v3 = *(const unsigned*)(hp + (size_t)s3 * HID);
    ax += (bf2f(v0 & 0xffff) + bf2f(v1 & 0xffff)) + (bf2f(v2 & 0xffff) + bf2f(v3 & 0xffff));
    ay += (bf2f(v0 >> 16) + bf2f(v1 >> 16)) + (bf2f(v2 >> 16) + bf2f(v3 >> 16));
  }
  for (; k < end; ++k) {
    int s = csr[k];
    unsigned v = *(const unsigned*)(hp + (size_t)s * HID);
    ax += bf2f(v & 0xffff);
    ay += bf2f(v >> 16);
  }
  float inv = 1.0f / fmaxf((float)(end - beg), 1.0f);
  unsigned o = (unsigned)f2bf(ax * inv) | ((unsigned)f2bf(ay * inv) << 16);
  *(unsigned*)(out + (size_t)wid * HID + 2 * lane) = o;
}

// ---------------------------------------------------------------------------
// layer1 (K=8, f32 in, bf16 out)
// ---------------------------------------------------------------------------
__global__ __launch_bounds__(256) void layer1_kernel(const float* __restrict__ agg8,
                                                     const float* __restrict__ gx,
                                                     const float* __restrict__ Wl,
                                                     const float* __restrict__ Wr,
                                                     const float* __restrict__ b,
                                                     unsigned short* __restrict__ out) {
  __shared__ float wl[8][128];
  __shared__ float wr[8][128];
  for (int t = threadIdx.x; t < 1024; t += 256) {
    int j = t >> 3, k = t & 7;
    wl[k][j] = Wl[t];
    wr[k][j] = Wr[t];
  }
  __syncthreads();
  int t = blockIdx.x * blockDim.x + threadIdx.x;
  int i = t >> 7;
  int j = t & 127;
  if (i >= N_NODES) return;
  const float* a = agg8 + (size_t)i * 8;
  const float* g = gx + (size_t)i * 8;
  float acc = b[j];
#pragma unroll
  for (int k = 0; k < 8; ++k) acc += a[k] * wl[k][j] + g[k] * wr[k][j];
  out[(size_t)i * HID + j] = f2bf(fmaxf(acc, 0.0f));
}

// ---------------------------------------------------------------------------
// pack Wl,Wr (f32 [128][128]) -> bf16 Wb [j][k] with k<128 -> Wl, k>=128 -> Wr
// ---------------------------------------------------------------------------
__global__ void pack_w_kernel(const float* __restrict__ Wl, const float* __restrict__ Wr,
                              unsigned short* __restrict__ Wb) {
  int t = blockIdx.x * blockDim.x + threadIdx.x;
  if (t >= 128 * 256) return;
  int j = t >> 8, k = t & 255;
  float v = (k < 128) ? Wl[j * 128 + k] : Wr[j * 128 + (k - 128)];
  Wb[t] = f2bf(v);
}

// ---------------------------------------------------------------------------
// MFMA SAGE GEMM: C[i][j] = act( sum_{k<128} A1[i][k] Wb[j][k]
//                              + sum_{k>=128} A2[i][k-128] Wb[j][k] + bias[j] )
// bf16 inputs, f32 accum, bf16 out. BM=128, BN=128, BK=32, 4 waves,
// wave = 32 rows x 128 cols = 2x8 frags of 16x16x32.
// ---------------------------------------------------------------------------
__global__ __launch_bounds__(256) void sage_gemm_mfma_kernel(
    const unsigned short* __restrict__ A1, const unsigned short* __restrict__ A2,
    const unsigned short* __restrict__ Wb, const float* __restrict__ bias,
    unsigned short* __restrict__ C, int M, int do_relu) {
  __shared__ unsigned short Alds[128 * LDSP];
  __shared__ unsigned short Wlds[128 * LDSP];
  int tid = threadIdx.x;
  int wave = tid >> 6, lane = tid & 63;
  int l15 = lane & 15, g = lane >> 4;
  int row0 = blockIdx.x * 128;

  f32x4 acc[2][8];
#pragma unroll
  for (int m = 0; m < 2; ++m)
#pragma unroll
    for (int n = 0; n < 8; ++n) acc[m][n] = (f32x4){0.f, 0.f, 0.f, 0.f};

  for (int ks = 0; ks < 8; ++ks) {
    const unsigned short* Asrc = (ks < 4) ? A1 : A2;
    int k0 = (ks & 3) * 32;
#pragma unroll
    for (int it = 0; it < 2; ++it) {
      int c = tid + it * 256;      // 0..511
      int r = c >> 2, cc = c & 3;  // row, 16B chunk
      int gr = row0 + r;
      u16x8 v = {};
      if (gr < M) v = *(const u16x8*)(Asrc + (size_t)gr * HID + k0 + cc * 8);
      *(u16x8*)(&Alds[r * LDSP + cc * 8]) = v;
      u16x8 wv = *(const u16x8*)(Wb + r * 256 + ks * 32 + cc * 8);
      *(u16x8*)(&Wlds[r * LDSP + cc * 8]) = wv;
    }
    __syncthreads();

    bf16x8 a[2], w[8];
    int mrow = wave * 32;
#pragma unroll
    for (int m = 0; m < 2; ++m)
      a[m] = __builtin_bit_cast(bf16x8,
             *(const u16x8*)(&Alds[(mrow + 16 * m + l15) * LDSP + g * 8]));
#pragma unroll
    for (int n = 0; n < 8; ++n)
      w[n] = __builtin_bit_cast(bf16x8,
             *(const u16x8*)(&Wlds[(16 * n + l15) * LDSP + g * 8]));
#pragma unroll
    for (int m = 0; m < 2; ++m)
#pragma unroll
      for (int n = 0; n < 8; ++n)
        acc[m][n] = __builtin_amdgcn_mfma_f32_16x16x32_bf16(a[m], w[n], acc[m][n], 0, 0, 0);
    __syncthreads();
  }

#pragma unroll
  for (int n = 0; n < 8; ++n) {
    int col = 16 * n + l15;
    float bv = bias[col];
#pragma unroll
    for (int m = 0; m < 2; ++m) {
#pragma unroll
      for (int r = 0; r < 4; ++r) {
        int grow = row0 + wave * 32 + 16 * m + g * 4 + r;
        if (grow < M) {
          float v = acc[m][n][r] + bv;
          if (do_relu) v = fmaxf(v, 0.0f);
          C[(size_t)grow * HID + col] = f2bf(v);
        }
      }
    }
  }
}

// ---------------------------------------------------------------------------
// layer4 projections (h bf16) + scalar aggregation
// ---------------------------------------------------------------------------
__global__ __launch_bounds__(256) void zzr_bf16_kernel(const unsigned short* __restrict__ h,
                                                       const float* __restrict__ Wl4,
                                                       const float* __restrict__ Wr4,
                                                       float* __restrict__ z,
                                                       float* __restrict__ zr) {
  int wid = (blockIdx.x * blockDim.x + threadIdx.x) >> 6;
  int lane = threadIdx.x & 63;
  if (wid >= N_NODES) return;
  unsigned v = *(const unsigned*)(h + (size_t)wid * HID + 2 * lane);
  float vx = bf2f(v & 0xffff), vy = bf2f(v >> 16);
  float2 wl = *(const float2*)(Wl4 + 2 * lane);
  float2 wr = *(const float2*)(Wr4 + 2 * lane);
  float a = vx * wl.x + vy * wl.y;
  float b = vx * wr.x + vy * wr.y;
#pragma unroll
  for (int off = 32; off > 0; off >>= 1) {
    a += __shfl_xor(a, off, 64);
    b += __shfl_xor(b, off, 64);
  }
  if (lane == 0) {
    z[wid] = a;
    zr[wid] = b;
  }
}

__global__ void gout_kernel(const float* __restrict__ z, const float* __restrict__ zr,
                            const int* __restrict__ row_ptr, const int* __restrict__ csr,
                            const float* __restrict__ bs4, float* __restrict__ gout) {
  int i = blockIdx.x * blockDim.x + threadIdx.x;
  if (i >= N_NODES) return;
  int beg = row_ptr[i], end = row_ptr[i + 1];
  float s = 0.0f;
  int k = beg;
  for (; k + 2 <= end; k += 2) s += z[csr[k]] + z[csr[k + 1]];
  for (; k < end; ++k) s += z[csr[k]];
  float d = fmaxf((float)(end - beg), 1.0f);
  gout[i] = s / d + zr[i] + bs4[0];
}

// ---------------------------------------------------------------------------
extern "C" void kernel_launch(void* const* d_in, const int* in_sizes, int n_in,
                              void* d_out, int out_size, void* d_ws, size_t ws_size,
                              hipStream_t stream) {
  const float* xdata = (const float*)d_in[0];
  const float* x = (const float*)d_in[1];
  const float* pos = (const float*)d_in[2];
  const int* ei = (const int*)d_in[3];
  const int* batch = (const int*)d_in[4];
  const float* w1 = (const float*)d_in[5];
  const float* b1 = (const float*)d_in[6];
  const float* w2 = (const float*)d_in[7];
  const float* b2 = (const float*)d_in[8];
  const float* w3 = (const float*)d_in[9];
  const float* b3 = (const float*)d_in[10];
  const float* Wl1 = (const float*)d_in[11];
  const float* Wr1 = (const float*)d_in[12];
  const float* bs1 = (const float*)d_in[13];
  const float* Wl2 = (const float*)d_in[14];
  const float* Wr2 = (const float*)d_in[15];
  const float* bs2 = (const float*)d_in[16];
  const float* Wl3 = (const float*)d_in[17];
  const float* Wr3 = (const float*)d_in[18];
  const float* bs3 = (const float*)d_in[19];
  const float* Wl4 = (const float*)d_in[20];
  const float* Wr4 = (const float*)d_in[21];
  const float* bs4 = (const float*)d_in[22];

  float* x1_out = (float*)d_out;                       // 32*1*128*128
  float* gout = (float*)d_out + (size_t)NBATCH * IMG;  // N

  char* ws = (char*)d_ws;
  size_t off = 0;
  auto take = [&](size_t bytes) -> char* {
    char* p = ws + off;
    off = (off + bytes + 255) & ~(size_t)255;
    return p;
  };
  float* hbuf1 = (float*)take((size_t)NBATCH * 16 * IMG * 4);  // conv h1 / bf16 h1,h3
  float* hbuf2 = (float*)take((size_t)NBATCH * 16 * IMG * 4);  // conv h2 / bf16 h2
  unsigned short* aggb = (unsigned short*)take((size_t)N_NODES * HID * 2);
  float* agg8o = (float*)take((size_t)N_NODES * 8 * 4);
  float* gx = (float*)take((size_t)N_NODES * 8 * 4);
  int* hist = (int*)take((size_t)N_NODES * 4);
  int* scanbuf = (int*)take((size_t)N_NODES * 4);
  int* partials = (int*)take((size_t)NSCAN * 4);
  int* row_ptr = (int*)take((size_t)(N_NODES + 1) * 4);
  int* cursor = (int*)take((size_t)N_NODES * 4);
  int* csr = (int*)take((size_t)N_EDGES * 4);
  float* z = (float*)take((size_t)N_NODES * 4);
  float* zr = (float*)take((size_t)N_NODES * 4);
  unsigned short* Wb2 = (unsigned short*)take((size_t)128 * 256 * 2);
  unsigned short* Wb3 = (unsigned short*)take((size_t)128 * 256 * 2);
  (void)ws_size;

  unsigned short* h1 = (unsigned short*)hbuf1;
  unsigned short* h2 = (unsigned short*)hbuf2;
  unsigned short* h3 = (unsigned short*)hbuf1;  // reuse after h1 consumed

  const int nblk_n = (N_NODES + 255) / 256;
  const int nblk_e = (N_EDGES + 255) / 256;
  const int nblk_conv = NBATCH * 16;
  const int nblk_gemm = (N_NODES + 127) / 128;  // 391

  // ---- CNN stack (f32, exact) ----
  hipLaunchKernelGGL((conv3x3_rb_kernel<8, 16, true>), dim3(nblk_conv), dim3(256), 0, stream,
                     xdata, w1, b1, hbuf1);
  hipLaunchKernelGGL((conv3x3_rb_kernel<16, 16, true>), dim3(nblk_conv), dim3(256), 0, stream,
                     hbuf1, w2, b2, hbuf2);
  hipLaunchKernelGGL((conv3x3_rb_kernel<16, 1, false>), dim3(nblk_conv), dim3(256), 0, stream,
                     hbuf2, w3, b3, x1_out);

  // ---- weight packs (tiny) ----
  hipLaunchKernelGGL(pack_w_kernel, dim3(128), dim3(256), 0, stream, Wl2, Wr2, Wb2);
  hipLaunchKernelGGL(pack_w_kernel, dim3(128), dim3(256), 0, stream, Wl3, Wr3, Wb3);

  // ---- CSR build ----
  hipLaunchKernelGGL(zero_int_kernel, dim3(nblk_n), dim3(256), 0, stream, hist, N_NODES);
  hipLaunchKernelGGL(hist_kernel, dim3(nblk_e), dim3(256), 0, stream, ei, hist);
  hipLaunchKernelGGL(scan_local_kernel, dim3(NSCAN), dim3(SCAN_BLK), 0, stream, hist, scanbuf,
                     partials);
  hipLaunchKernelGGL(scan_partials_kernel, dim3(1), dim3(64), 0, stream, partials);
  hipLaunchKernelGGL(scan_add_kernel, dim3(nblk_n), dim3(256), 0, stream, scanbuf, partials,
                     row_ptr, cursor);
  hipLaunchKernelGGL(scatter_kernel, dim3(nblk_e), dim3(256), 0, stream, ei, cursor, csr);

  // ---- node features ----
  hipLaunchKernelGGL(gather_gx_kernel, dim3(nblk_n), dim3(256), 0, stream, x, pos, batch,
                     x1_out, gx);

  // ---- layer 1 (K=8) -> h1 bf16 ----
  hipLaunchKernelGGL(agg8_kernel, dim3((N_NODES * 8 + 255) / 256), dim3(256), 0, stream, gx,
                     row_ptr, csr, agg8o);
  hipLaunchKernelGGL(layer1_kernel, dim3((N_NODES * 128) / 256), dim3(256), 0, stream, agg8o,
                     gx, Wl1, Wr1, bs1, h1);

  // ---- layer 2 ----
  hipLaunchKernelGGL(agg128_bf16_kernel, dim3(N_NODES / 4), dim3(256), 0, stream, h1, row_ptr,
                     csr, aggb);
  hipLaunchKernelGGL(sage_gemm_mfma_kernel, dim3(nblk_gemm), dim3(256), 0, stream, aggb, h1,
                     Wb2, bs2, h2, N_NODES, 1);

  // ---- layer 3 ----
  hipLaunchKernelGGL(agg128_bf16_kernel, dim3(N_NODES / 4), dim3(256), 0, stream, h2, row_ptr,
                     csr, aggb);
  hipLaunchKernelGGL(sage_gemm_mfma_kernel, dim3(nblk_gemm), dim3(256), 0, stream, aggb, h2,
                     Wb3, bs3, h3, N_NODES, 1);

  // ---- layer 4 ----
  hipLaunchKernelGGL(zzr_bf16_kernel, dim3(N_NODES / 4), dim3(256), 0, stream, h3, Wl4, Wr4, z,
                     zr);
  hipLaunchKernelGGL(gout_kernel, dim3(nblk_n), dim3(256), 0, stream, z, zr, row_ptr, csr, bs4,
                     gout);
}